// Round 6
// baseline (294.808 us; speedup 1.0000x reference)
//
#include <hip/hip_runtime.h>
#include <math.h>

typedef __bf16 bf16x8 __attribute__((ext_vector_type(8)));
typedef float f32x4 __attribute__((ext_vector_type(4)));
typedef unsigned short u16;
typedef unsigned int u32;

__device__ __forceinline__ u16 f2bf(float f) {
  u32 u = __float_as_uint(f);
  u32 r = u + 0x7FFF + ((u >> 16) & 1);
  return (u16)(r >> 16);
}
__device__ __forceinline__ float bf2f(u16 h) { return __uint_as_float(((u32)h) << 16); }

// ---------------- arena (byte offsets) ----------------
static constexpr size_t OB_WBF = 0;                       // 1,638,400 u16
static constexpr size_t OB_WPE = 3276800;                 // 2304 f32
static constexpr size_t OB_ST  = 3286016;                 // 6 x 4096B stat sums
static constexpr size_t OB_GV  = 3310592;                 // 256 f32
static constexpr size_t OB_GACC= 3311616;                 // 8 f32 gate accum
static constexpr size_t OB_CAT = 3311872;                 // bf16 [2][2304][1024]
static constexpr size_t OB_YA  = OB_CAT + 9437184;        // f32 gemm out (max 9.4MB)
static constexpr size_t OB_U1  = OB_YA + 9437184;         // xbf16 -> a1f f32 (4.7MB)
static constexpr size_t OB_U2  = OB_U1 + 4718592;         // qkv bf16 -> colb ; +ef f32
static constexpr size_t OB_U3  = OB_U2 + 14155776;        // rf f32 -> hb bf16 (4.7MB)
static constexpr size_t OB_AOB = OB_U3 + 4718592;         // attn out bf16 (2.36MB)
static constexpr size_t OB_A1B = OB_AOB + 2359296;        // a1 bf16 (2.36MB)
static constexpr size_t WS_TOTAL = OB_A1B + 2359296;      // ~50.5MB

// ---------------- weight prep: w = m*cos(p) -> bf16 (mproj tap-major remap) ----------------
struct WPrepP {
  const float* m[8]; const float* p[8];
  u16* out; const float* pem; const float* pep; float* peout;
  int cum[9];
};
__global__ __launch_bounds__(256) void k_wprep(WPrepP P) {
  int i = blockIdx.x * 256 + threadIdx.x;
  if (i < 2304) P.peout[i] = P.pem[i] * cosf(P.pep[i]);
  if (i >= P.cum[8]) return;
  int s = 0;
  while (s < 7 && i >= P.cum[s + 1]) s++;
  int j = i - P.cum[s];
  int src = j;
  if (s == 6) {  // mproj: out[o][kk*128+cc] <- in[(o*128+cc)*9+kk]
    int o = j / 1152, r = j % 1152, kk = r >> 7, cc = r & 127;
    src = (o * 128 + cc) * 9 + kk;
  }
  P.out[i] = f2bf(P.m[s][src] * cosf(P.p[s][src]));
}

// ---------------- x transpose: [b][c][q][hw] f32 -> [b][q*576+hw][c] bf16 ----------------
__global__ __launch_bounds__(256) void k_xpose(const float* x, u16* xb) {
  int bid = blockIdx.x;
  int mt = bid % 18; bid /= 18;
  int ct = bid % 16; bid /= 16;
  int q = bid & 3, b = bid >> 2;
  __shared__ float tile[32][33];
  int tj = threadIdx.x & 31, ti = threadIdx.x >> 5;
  const float* xp = x + (((size_t)(b * 512 + ct * 32) * 4 + q) * 576) + mt * 32;
#pragma unroll
  for (int ii = 0; ii < 4; ii++)
    tile[ti + ii * 8][tj] = xp[(size_t)(ti + ii * 8) * 4 * 576 + tj];
  __syncthreads();
  u16* yp = xb + ((size_t)b * 2304 + q * 576 + mt * 32) * 512 + ct * 32;
#pragma unroll
  for (int mm = 0; mm < 4; mm++)
    yp[(size_t)(mm * 8 + ti) * 512 + tj] = f2bf(tile[tj][mm * 8 + ti]);
}

// ---------------- MFMA GEMM: Y[g][m][o] = sum_k W[o][k] X[g][m][k] (+fused BN sums) --------
// Staging via global_load_lds (linear LDS dest, inverse-swizzled global source, rule #21):
// slot s -> row = s>>3, kg = (s&7) ^ (row&7); reads use the same XOR involution.
struct GemmP {
  const u16* W; const u16* X; float* Y; const float* Add; u16* Yb; float* St;
  long long xOff[8];
  int lda, O, K, M, G;
};

template <int BM, int NWO, int WO, int WM>
__global__ __launch_bounds__(256) void k_gemm(GemmP P) {
  constexpr int FO = WO / 16, FM = WM / 16;
  __shared__ __align__(16) char lds[16384 + BM * 128];
  const int mt = P.M / BM;
  const int ot = P.O >> 7;
  int bid = blockIdx.x;
  const int g = bid / (mt * ot);
  const int rr = bid % (mt * ot);
  const int ob = (rr / mt) << 7;
  const int mb = (rr % mt) * BM;
  const int t = threadIdx.x, lane = t & 63, wave = t >> 6;
  const int wo = (wave % NWO) * WO, wm = (wave / NWO) * WM;
  const u16* Wp = P.W + (size_t)ob * P.K;
  const u16* Xp = P.X + P.xOff[g] + (size_t)mb * P.lda;

  f32x4 acc[FO][FM] = {};

  for (int k0 = 0; k0 < P.K; k0 += 64) {
    // A: 128 rows x 64 k = 1024 slots of 16B; 4 calls/wave, wave-uniform LDS base
#pragma unroll
    for (int i = 0; i < 4; i++) {
      int s = (i * 4 + wave) * 64 + lane;
      int row = s >> 3;
      int kg = (s & 7) ^ (row & 7);
      const u16* src = Wp + (size_t)row * P.K + k0 + kg * 8;
      __builtin_amdgcn_global_load_lds(
          (const __attribute__((address_space(1))) u32*)src,
          (__attribute__((address_space(3))) u32*)(lds + (size_t)(i * 4 + wave) * 1024),
          16, 0, 0);
    }
    // B: BM rows x 64 k = BM*8 slots
#pragma unroll
    for (int i = 0; i < BM * 8 / 256; i++) {
      int s = (i * 4 + wave) * 64 + lane;
      int row = s >> 3;
      int kg = (s & 7) ^ (row & 7);
      const u16* src = Xp + (size_t)row * P.lda + k0 + kg * 8;
      __builtin_amdgcn_global_load_lds(
          (const __attribute__((address_space(1))) u32*)src,
          (__attribute__((address_space(3))) u32*)(lds + 16384 + (size_t)(i * 4 + wave) * 1024),
          16, 0, 0);
    }
    __syncthreads();
#pragma unroll
    for (int kk = 0; kk < 2; kk++) {
      int kgl = kk * 4 + (lane >> 4);
      bf16x8 af[FO], bfm[FM];
#pragma unroll
      for (int fo = 0; fo < FO; fo++) {
        int row = wo + fo * 16 + (lane & 15);
        af[fo] = *(bf16x8*)&lds[((row << 3) + (kgl ^ (row & 7))) << 4];
      }
#pragma unroll
      for (int fm = 0; fm < FM; fm++) {
        int row = wm + fm * 16 + (lane & 15);
        bfm[fm] = *(bf16x8*)&lds[16384 + (((row << 3) + (kgl ^ (row & 7))) << 4)];
      }
#pragma unroll
      for (int fo = 0; fo < FO; fo++)
#pragma unroll
        for (int fm = 0; fm < FM; fm++)
          acc[fo][fm] = __builtin_amdgcn_mfma_f32_16x16x32_bf16(af[fo], bfm[fm], acc[fo][fm], 0, 0, 0);
    }
    __syncthreads();
  }

  size_t ybase = (size_t)g * P.M * P.O;
#pragma unroll
  for (int fo = 0; fo < FO; fo++) {
    int ow = ob + wo + fo * 16 + ((lane >> 4) << 2);
#pragma unroll
    for (int fm = 0; fm < FM; fm++) {
      int m = mb + wm + fm * 16 + (lane & 15);
      f32x4 v = acc[fo][fm];
      size_t off = ybase + (size_t)m * P.O + ow;
      if (P.Add) v += *(const f32x4*)&P.Add[off];
      if (P.Y) *(f32x4*)&P.Y[off] = v;
      if (P.Yb) {
        ushort4 r;
        r.x = f2bf(v[0]); r.y = f2bf(v[1]); r.z = f2bf(v[2]); r.w = f2bf(v[3]);
        *(ushort4*)&P.Yb[off] = r;
      }
    }
  }

  // fused BN partial sums: per channel o, sum/sumsq over this block's m-slice
  if (P.St) {
#pragma unroll
    for (int fo = 0; fo < FO; fo++) {
      float sv[4], qv[4];
#pragma unroll
      for (int j = 0; j < 4; j++) { sv[j] = 0.f; qv[j] = 0.f; }
#pragma unroll
      for (int fm = 0; fm < FM; fm++)
#pragma unroll
        for (int j = 0; j < 4; j++) {
          float a = acc[fo][fm][j];
          sv[j] += a;
          qv[j] = fmaf(a, a, qv[j]);
        }
#pragma unroll
      for (int j = 0; j < 4; j++) {
#pragma unroll
        for (int mk = 1; mk < 16; mk <<= 1) {
          sv[j] += __shfl_xor(sv[j], mk, 64);
          qv[j] += __shfl_xor(qv[j], mk, 64);
        }
      }
      if ((lane & 15) == 0) {
        int o = ob + wo + fo * 16 + ((lane >> 4) << 2);
#pragma unroll
        for (int j = 0; j < 4; j++) {
          atomicAdd(&P.St[2 * (o + j)], sv[j]);
          atomicAdd(&P.St[2 * (o + j) + 1], qv[j]);
        }
      }
    }
  }
}

// ---------------- BN normalize from raw sums (+add, relu, opt gate accum) ----------------
struct NormP {
  const float* X; const float* st; const float* Add;
  u16* Yb; float* Yf; const float* gv; float* gacc;
  long long ybOff[8];
  int ldyb, O, G, M, relu;
  float n;
};
__global__ __launch_bounds__(256) void k_norm(NormP P) {
  int O4 = P.O >> 2;
  long long idx = (long long)blockIdx.x * 256 + threadIdx.x;
  if (idx >= (long long)P.G * P.M * O4) return;
  int c4 = (int)(idx % O4);
  long long gm = idx / O4;
  int m = (int)(gm % P.M);
  int g = (int)(gm / P.M);
  size_t off = (size_t)gm * P.O + c4 * 4;
  f32x4 v = *(const f32x4*)&P.X[off];
  float inv_n = 1.0f / P.n;
#pragma unroll
  for (int j = 0; j < 4; j++) {
    int c = c4 * 4 + j;
    float mean = P.st[2 * c] * inv_n;
    float var = P.st[2 * c + 1] * inv_n - mean * mean;
    v[j] = (v[j] - mean) * rsqrtf(var + 1e-5f);
  }
  if (P.Add) v += *(const f32x4*)&P.Add[off];
  if (P.relu) {
#pragma unroll
    for (int j = 0; j < 4; j++) v[j] = fmaxf(v[j], 0.f);
  }
  if (P.Yb) {
    ushort4 r;
    r.x = f2bf(v[0]); r.y = f2bf(v[1]); r.z = f2bf(v[2]); r.w = f2bf(v[3]);
    *(ushort4*)(P.Yb + P.ybOff[g] + (size_t)m * P.ldyb + c4 * 4) = r;
  }
  if (P.Yf) *(f32x4*)&P.Yf[off] = v;
  if (P.gacc) {  // block covers a single (g,q); accumulate e·gv
    float gs = 0.f;
#pragma unroll
    for (int j = 0; j < 4; j++) gs = fmaf(v[j], P.gv[g * 128 + c4 * 4 + j], gs);
#pragma unroll
    for (int mk = 1; mk < 64; mk <<= 1) gs += __shfl_xor(gs, mk, 64);
    __shared__ float t1[4];
    int lane = threadIdx.x & 63, wv = threadIdx.x >> 6;
    if (lane == 0) t1[wv] = gs;
    __syncthreads();
    if (threadIdx.x == 0)
      atomicAdd(&P.gacc[g * 4 + m / 576], t1[0] + t1[1] + t1[2] + t1[3]);
  }
}

// ---------------- final norm (raw sums) with transpose to [b][o][q][hw] f32 ----------------
__global__ __launch_bounds__(256) void k_normT(const float* X, const float* st, float* out) {
  int idx = blockIdx.x * 256 + threadIdx.x;  // (b*512+o)*576 + m4
  if (idx >= 2 * 512 * 576) return;
  int m4 = idx % 576;
  int bo = idx / 576;
  int o = bo & 511, b = bo >> 9;
  float inv_n = 1.0f / 4608.0f;
  float mean = st[2 * o] * inv_n;
  float var = st[2 * o + 1] * inv_n - mean * mean;
  float rs = rsqrtf(var + 1e-5f);
  f32x4 v;
#pragma unroll
  for (int j = 0; j < 4; j++) {
    float x = X[((size_t)b * 2304 + m4 * 4 + j) * 512 + o];
    v[j] = fmaxf((x - mean) * rs, 0.f);
  }
  *(f32x4*)&out[(size_t)bo * 2304 + m4 * 4] = v;
}

// ---------------- depthwise 3x3 pe + residual: rf[g][m][c] = dw(b)+b ----------------
__global__ __launch_bounds__(256) void k_pe(const u16* catb, const float* wpe, float* rf) {
  int idx = blockIdx.x * 256 + threadIdx.x;  // (g*2304+m)*64 + c4
  if (idx >= 2 * 2304 * 64) return;
  int c4 = idx & 63;
  int gm = idx >> 6;
  int m = gm % 2304, g = gm / 2304;
  int q = m / 576, hw = m % 576, h = hw / 24, w = hw % 24;
  const u16* base = catb + (size_t)g * 2304 * 1024 + 256 + c4 * 4;
  float acc[4];
  {
    ushort4 cv = *(const ushort4*)(base + (size_t)m * 1024);
    acc[0] = bf2f(cv.x); acc[1] = bf2f(cv.y); acc[2] = bf2f(cv.z); acc[3] = bf2f(cv.w);
  }
#pragma unroll
  for (int kh = 0; kh < 3; kh++) {
    int hh = h + kh - 1;
    if (hh < 0 || hh > 23) continue;
#pragma unroll
    for (int kw = 0; kw < 3; kw++) {
      int ww = w + kw - 1;
      if (ww < 0 || ww > 23) continue;
      ushort4 cv = *(const ushort4*)(base + (size_t)(q * 576 + hh * 24 + ww) * 1024);
      float tap[4] = {bf2f(cv.x), bf2f(cv.y), bf2f(cv.z), bf2f(cv.w)};
#pragma unroll
      for (int j = 0; j < 4; j++)
        acc[j] = fmaf(wpe[(c4 * 4 + j) * 9 + kh * 3 + kw], tap[j], acc[j]);
    }
  }
  f32x4 v = {acc[0], acc[1], acc[2], acc[3]};
  *(f32x4*)&rf[(size_t)gm * 256 + c4 * 4] = v;
}

// ---------------- MFMA flash attention (no-max softmax; scores tiny) ----------------
__global__ __launch_bounds__(256) void k_attn(const u16* qkv, u16* ao) {
  int bid = blockIdx.x;
  int tq = bid % 3; int u = bid / 3;
  int qd = u & 3; u >>= 2;
  int head = u & 15, b = u >> 4;
  int t = threadIdx.x, lane = t & 63, wv = t >> 6;
  int g = lane >> 4, q = lane & 15;
  size_t tok0 = (size_t)b * 2304 + qd * 576;
  const u16* QKV = qkv + tok0 * 768;

  __shared__ __align__(16) char shm[50176];
  u16* Kl = (u16*)(shm);                       // [576][24]
  u16* VT = (u16*)(shm + 27648);               // [(m>>3)][d][m&7]
  u16* Pl = (u16*)(shm + 46080 + wv * 1024);   // [4][16][8]

  for (int i = t; i < 1152; i += 256) {
    int m = i >> 1, half = i & 1;
    const u16* src = QKV + (size_t)m * 768 + 256 + head * 16 + half * 8;
    u16 tmp[8];
    *(uint4*)tmp = *(const uint4*)src;
    ushort4 lo, hi;
    lo.x = f2bf(bf2f(tmp[0]) * 0.25f); lo.y = f2bf(bf2f(tmp[1]) * 0.25f);
    lo.z = f2bf(bf2f(tmp[2]) * 0.25f); lo.w = f2bf(bf2f(tmp[3]) * 0.25f);
    hi.x = f2bf(bf2f(tmp[4]) * 0.25f); hi.y = f2bf(bf2f(tmp[5]) * 0.25f);
    hi.z = f2bf(bf2f(tmp[6]) * 0.25f); hi.w = f2bf(bf2f(tmp[7]) * 0.25f);
    u16* dst = Kl + m * 24 + half * 8;
    *(ushort4*)dst = lo;
    *(ushort4*)(dst + 4) = hi;
  }
  for (int mm = t; mm < 576; mm += 256) {
    const u16* src = QKV + (size_t)mm * 768 + 512 + head * 16;
    u16 tmp[16];
    *(uint4*)tmp = *(const uint4*)src;
    *(uint4*)(tmp + 8) = *(const uint4*)(src + 8);
    u16* dst = VT + (mm >> 3) * 128 + (mm & 7);
#pragma unroll
    for (int d = 0; d < 16; d++) dst[d * 8] = tmp[d];
  }
  __syncthreads();

#pragma unroll 1
  for (int i = 0; i < 3; i++) {
    int tl = wv * 3 + i;
    int qbase = tq * 192 + tl * 16;
    bf16x8 qf = {};
    if (g < 2)
      qf = *(const bf16x8*)(QKV + (size_t)(qbase + q) * 768 + head * 16 + g * 8);

    f32x4 acc_o = {};
    float ssum = 0.f;

    for (int ch = 0; ch < 18; ch++) {
      int m0 = ch * 32;
      f32x4 s[2];
#pragma unroll
      for (int h = 0; h < 2; h++) {
        bf16x8 kf = {};
        if (g < 2)
          kf = *(const bf16x8*)(Kl + (size_t)(m0 + h * 16 + q) * 24 + g * 8);
        f32x4 z = {};
        s[h] = __builtin_amdgcn_mfma_f32_16x16x32_bf16(kf, qf, z, 0, 0, 0);
      }
#pragma unroll
      for (int h = 0; h < 2; h++) {
        float p0 = __expf(s[h][0]);
        float p1 = __expf(s[h][1]);
        float p2 = __expf(s[h][2]);
        float p3 = __expf(s[h][3]);
        ssum += (p0 + p1) + (p2 + p3);
        ushort4 w;
        w.x = f2bf(p0); w.y = f2bf(p1); w.z = f2bf(p2); w.w = f2bf(p3);
        *(ushort4*)(Pl + ((h * 2 + (g >> 1)) * 16 + q) * 8 + (g & 1) * 4) = w;
      }
      bf16x8 va = *(const bf16x8*)(VT + ((m0 >> 3) + g) * 128 + q * 8);
      bf16x8 pa = *(const bf16x8*)(Pl + (g * 16 + q) * 8);
      acc_o = __builtin_amdgcn_mfma_f32_16x16x32_bf16(va, pa, acc_o, 0, 0, 0);
    }

    ssum += __shfl_xor(ssum, 16, 64);
    ssum += __shfl_xor(ssum, 32, 64);
    float inv = 1.f / ssum;
    u16* op = ao + (tok0 + qbase + q) * 256 + head * 16 + g * 4;
    ushort4 r;
    r.x = f2bf(acc_o[0] * inv);
    r.y = f2bf(acc_o[1] * inv);
    r.z = f2bf(acc_o[2] * inv);
    r.w = f2bf(acc_o[3] * inv);
    *(ushort4*)op = r;
  }
}

// ---------------- guide linear: one block per (b,e), 64-lane dot ----------------
__global__ __launch_bounds__(64) void k_guide(const float* guide, const float* glw,
                                              const float* glb, float* g) {
  int be = blockIdx.x;  // b*128+e
  int b = be >> 7, e = be & 127;
  const float* gr = guide + b * 512;
  const float* wr = glw + e * 512;
  float s = 0.f;
  for (int c = threadIdx.x; c < 512; c += 64) s = fmaf(gr[c], wr[c], s);
#pragma unroll
  for (int off = 32; off > 0; off >>= 1) s += __shfl_down(s, off, 64);
  if (threadIdx.x == 0) g[be] = s + glb[e];
}

// ---------------- im2col (gated, sigmoid inline, tap-major k) -> bf16 col ----------------
__global__ __launch_bounds__(256) void k_im2col(const float* ef, const float* gacc, u16* col) {
  int idx = blockIdx.x * 256 + threadIdx.x;  // (g*576+n)*9+kk
  if (idx >= 8 * 576 * 9) return;
  int kk = idx % 9;
  int gn = idx / 9;
  int n = gn % 576, g = gn / 576;
  int b = g >> 2, q = g & 3;
  int h = n / 24 + kk / 3 - 1, w = n % 24 + kk % 3 - 1;
  u16* cp = col + (size_t)gn * 1152 + kk * 128;
  if (h < 0 || h > 23 || w < 0 || w > 23) {
    ushort4 z = {0, 0, 0, 0};
#pragma unroll
    for (int c4 = 0; c4 < 32; c4++) *(ushort4*)&cp[c4 * 4] = z;
    return;
  }
  float a = gacc[g] / sqrtf(73728.0f);
  float gt = 1.f / (1.f + expf(-a));
  const float* ep = ef + ((size_t)b * 2304 + q * 576 + h * 24 + w) * 128;
  for (int c4 = 0; c4 < 32; c4++) {
    f32x4 v = *(const f32x4*)&ep[c4 * 4];
    ushort4 r;
    r.x = f2bf(v[0] * gt); r.y = f2bf(v[1] * gt);
    r.z = f2bf(v[2] * gt); r.w = f2bf(v[3] * gt);
    *(ushort4*)&cp[c4 * 4] = r;
  }
}

// ---------------- host ----------------
extern "C" void kernel_launch(void* const* d_in, const int* in_sizes, int n_in,
                              void* d_out, int out_size, void* d_ws, size_t ws_size,
                              hipStream_t stream) {
  if (ws_size < WS_TOTAL) return;
  char* ws = (char*)d_ws;
  u16* WB = (u16*)(ws + OB_WBF);
  float* WPE = (float*)(ws + OB_WPE);
  float* STB = (float*)(ws + OB_ST);
  float* GV = (float*)(ws + OB_GV);
  float* GACC = (float*)(ws + OB_GACC);
  u16* CATB = (u16*)(ws + OB_CAT);
  float* YA = (float*)(ws + OB_YA);
  u16* XBF = (u16*)(ws + OB_U1);
  float* A1F = (float*)(ws + OB_U1);
  u16* QKVB = (u16*)(ws + OB_U2);
  u16* COLB = (u16*)(ws + OB_U2);
  float* EF = (float*)(ws + OB_U2 + 10616832);
  float* RF = (float*)(ws + OB_U3);
  u16* HB = (u16*)(ws + OB_U3);
  u16* AOB = (u16*)(ws + OB_AOB);
  u16* A1B = (u16*)(ws + OB_A1B);
  float* out = (float*)d_out;
  const float* x = (const float*)d_in[0];
  const float* guide = (const float*)d_in[1];
  const float* glw = (const float*)d_in[16];
  const float* glb = (const float*)d_in[17];

  // zero stat sums + GV + GACC
  hipMemsetAsync(ws + OB_ST, 0, OB_CAT - OB_ST, stream);

  {  // weights
    WPrepP p;
    const int mi[8] = {2, 4, 6, 10, 12, 14, 18, 20};
    const int sz[8] = {262144, 196608, 65536, 131072, 131072, 32768, 294912, 524288};
    int c = 0;
    for (int i = 0; i < 8; i++) {
      p.m[i] = (const float*)d_in[mi[i]];
      p.p[i] = (const float*)d_in[mi[i] + 1];
      p.cum[i] = c;
      c += sz[i];
    }
    p.cum[8] = c;
    p.out = WB;
    p.pem = (const float*)d_in[8];
    p.pep = (const float*)d_in[9];
    p.peout = WPE;
    k_wprep<<<(c + 255) / 256, 256, 0, stream>>>(p);
  }
  k_guide<<<256, 64, 0, stream>>>(guide, glw, glb, GV);
  k_xpose<<<2304, 256, 0, stream>>>(x, XBF);

  auto gemm = [&](size_t wOff, int O, int K, int M, int G,
                  const u16* X, long long xs, long long xadd, int lda,
                  float* Y, const float* Add, u16* Yb, int si) {
    GemmP p;
    p.W = WB + wOff; p.X = X; p.Y = Y; p.Add = Add; p.Yb = Yb;
    p.St = (si >= 0) ? (STB + si * 1024) : nullptr;
    p.lda = lda; p.O = O; p.K = K; p.M = M; p.G = G;
    for (int g = 0; g < 8; g++) p.xOff[g] = (long long)(g < G ? g : 0) * xs + xadd;
    int grid = G * (O / 128) * (M / 64);
    k_gemm<64, 4, 32, 64><<<grid, 256, 0, stream>>>(p);
  };
  auto norm = [&](const float* X, int si, int O, int G, int M, const float* Add,
                  u16* Yb, int ldyb, const long long* ybOff, float* Yf, int relu,
                  const float* gv, float* gacc) {
    NormP p;
    p.X = X; p.st = STB + si * 1024; p.Add = Add; p.Yb = Yb; p.Yf = Yf;
    p.gv = gv; p.gacc = gacc;
    p.ldyb = ldyb; p.O = O; p.G = G; p.M = M; p.relu = relu;
    p.n = (float)(G * M);
    for (int g = 0; g < 8; g++) p.ybOff[g] = ybOff ? ybOff[(g < G) ? g : 0] : 0;
    long long total = (long long)G * M * (O / 4);
    k_norm<<<(int)((total + 255) / 256), 256, 0, stream>>>(p);
  };

  // cv1 -> bn relu -> cat[0:512]
  gemm(0, 512, 512, 2304, 2, XBF, 2304LL * 512, 0, 512, YA, nullptr, nullptr, 0);
  { long long yo[2] = {0, 2304LL * 1024};
    norm(YA, 0, 512, 2, 2304, nullptr, CATB, 1024, yo, nullptr, 1, nullptr, nullptr); }

  // qkv (bf16 only)
  gemm(262144, 768, 256, 2304, 2, CATB, 2304LL * 1024, 256, 1024, nullptr, nullptr, QKVB, -1);
  // MFMA flash attention
  k_attn<<<384, 256, 0, stream>>>(QKVB, AOB);
  // pe + residual
  k_pe<<<1152, 256, 0, stream>>>(CATB, WPE, RF);
  // aproj (+rf) -> a1 (f32 + bf16)
  gemm(458752, 256, 256, 2304, 2, AOB, 2304LL * 256, 0, 256, A1F, RF, A1B, -1);

  // ffn1 -> bn relu -> hb
  gemm(524288, 512, 256, 2304, 2, A1B, 2304LL * 256, 0, 256, YA, nullptr, nullptr, 1);
  { long long yo[2] = {0, 2304LL * 512};
    norm(YA, 1, 512, 2, 2304, nullptr, HB, 512, yo, nullptr, 1, nullptr, nullptr); }

  // ffn2 -> bn -> +a1 -> cat[512:768]
  gemm(655360, 256, 512, 2304, 2, HB, 2304LL * 512, 0, 512, YA, nullptr, nullptr, 2);
  { long long yo[2] = {512, 2304LL * 1024 + 512};
    norm(YA, 2, 256, 2, 2304, A1F, CATB, 1024, yo, nullptr, 0, nullptr, nullptr); }

  // ec -> bn relu -> ef (f32) + fused gate partials
  gemm(786432, 128, 256, 2304, 2, CATB, 2304LL * 1024, 512, 1024, YA, nullptr, nullptr, 3);
  norm(YA, 3, 128, 2, 2304, nullptr, nullptr, 0, nullptr, EF, 1, GV, GACC);

  // im2col (sigmoid inline)
  k_im2col<<<162, 256, 0, stream>>>(EF, GACC, COLB);

  // mproj -> bn relu -> cat[768:1024]
  gemm(819200, 256, 1152, 576, 8, COLB, 576LL * 1152, 0, 1152, YA, nullptr, nullptr, 4);
  { long long yo[8];
    for (int g = 0; g < 8; g++)
      yo[g] = (long long)(g >> 2) * 2304 * 1024 + (long long)(g & 3) * 576 * 1024 + 768;
    norm(YA, 4, 256, 8, 576, nullptr, CATB, 1024, yo, nullptr, 1, nullptr, nullptr); }

  // cv2 -> bn relu -> out (transpose)
  gemm(1114112, 512, 1024, 2304, 2, CATB, 2304LL * 1024, 0, 1024, YA, nullptr, nullptr, 5);
  k_normT<<<2304, 256, 0, stream>>>(YA, STB + 5 * 1024, out);
}

// Round 7
// 273.036 us; speedup vs baseline: 1.0797x; 1.0797x over previous
//
#include <hip/hip_runtime.h>
#include <math.h>

typedef __bf16 bf16x8 __attribute__((ext_vector_type(8)));
typedef float f32x4 __attribute__((ext_vector_type(4)));
typedef unsigned short u16;
typedef unsigned int u32;

__device__ __forceinline__ u16 f2bf(float f) {
  u32 u = __float_as_uint(f);
  u32 r = u + 0x7FFF + ((u >> 16) & 1);
  return (u16)(r >> 16);
}
__device__ __forceinline__ float bf2f(u16 h) { return __uint_as_float(((u32)h) << 16); }

// ---------------- arena (byte offsets) ----------------
static constexpr size_t OB_WBF = 0;                       // 1,638,400 u16
static constexpr size_t OB_WPE = 3276800;                 // 2304 f32 ([9][256] tap-major)
static constexpr size_t OB_ST  = 3286016;                 // 6 x 4096B stat sums
static constexpr size_t OB_GV  = 3310592;                 // 256 f32
static constexpr size_t OB_GACC= 3311616;                 // 8 f32 gate accum
static constexpr size_t OB_CAT = 3311872;                 // bf16 [2][2304][1024]
static constexpr size_t OB_YA  = OB_CAT + 9437184;        // f32 gemm out (max 9.4MB)
static constexpr size_t OB_U1  = OB_YA + 9437184;         // xbf16 (4.7MB)
static constexpr size_t OB_U2  = OB_U1 + 4718592;         // qkv bf16 7.1MB ; +EF f32 at +10616832
static constexpr size_t OB_U3  = OB_U2 + 14155776;        // hb bf16 (4.7MB)
static constexpr size_t OB_AOB = OB_U3 + 4718592;         // attn out bf16 (2.36MB)
static constexpr size_t OB_A1B = OB_AOB + 2359296;        // a1 bf16 (2.36MB)
static constexpr size_t WS_TOTAL = OB_A1B + 2359296;      // ~50.5MB

// ---------------- head: wprep + x-transpose + guide linear, range-split ----------------
struct HeadP {
  const float* m[8]; const float* p[8]; u16* wout;
  const float* pem; const float* pep; float* peout;
  const float* x; u16* xb;
  const float* guide; const float* glw; const float* glb; float* gv;
  int cum[9]; int nwp;
};
__global__ __launch_bounds__(256) void k_head(HeadP P) {
  int bid = blockIdx.x;
  if (bid < P.nwp) {  // weight prep: w = m*cos(p) -> bf16 (mproj tap-major remap)
    int i = bid * 256 + threadIdx.x;
    if (i < 2304) {  // pe weights transposed [tap][256]
      int tap = i >> 8, c = i & 255;
      P.peout[i] = P.pem[c * 9 + tap] * cosf(P.pep[c * 9 + tap]);
    }
    if (i >= P.cum[8]) return;
    int s = 0;
    while (s < 7 && i >= P.cum[s + 1]) s++;
    int j = i - P.cum[s];
    int src = j;
    if (s == 6) {  // mproj: out[o][kk*128+cc] <- in[(o*128+cc)*9+kk]
      int o = j / 1152, r = j % 1152, kk = r >> 7, cc = r & 127;
      src = (o * 128 + cc) * 9 + kk;
    }
    P.wout[i] = f2bf(P.m[s][src] * cosf(P.p[s][src]));
    return;
  }
  bid -= P.nwp;
  if (bid < 2304) {  // x transpose: [b][c][q][hw] f32 -> [b][q*576+hw][c] bf16
    int mt = bid % 18; bid /= 18;
    int ct = bid % 16; bid /= 16;
    int q = bid & 3, b = bid >> 2;
    __shared__ float tile[32][33];
    int tj = threadIdx.x & 31, ti = threadIdx.x >> 5;
    const float* xp = P.x + (((size_t)(b * 512 + ct * 32) * 4 + q) * 576) + mt * 32;
#pragma unroll
    for (int ii = 0; ii < 4; ii++)
      tile[ti + ii * 8][tj] = xp[(size_t)(ti + ii * 8) * 4 * 576 + tj];
    __syncthreads();
    u16* yp = P.xb + ((size_t)b * 2304 + q * 576 + mt * 32) * 512 + ct * 32;
#pragma unroll
    for (int mm = 0; mm < 4; mm++)
      yp[(size_t)(mm * 8 + ti) * 512 + tj] = f2bf(tile[tj][mm * 8 + ti]);
    return;
  }
  bid -= 2304;  // guide: 64 blocks x 4 waves, one (b,e) per wave
  int wv = threadIdx.x >> 6, lane = threadIdx.x & 63;
  int be = bid * 4 + wv;
  int b = be >> 7, e = be & 127;
  const float* gr = P.guide + b * 512;
  const float* wr = P.glw + e * 512;
  float s = 0.f;
  for (int c = lane; c < 512; c += 64) s = fmaf(gr[c], wr[c], s);
#pragma unroll
  for (int off = 32; off > 0; off >>= 1) s += __shfl_down(s, off, 64);
  if (lane == 0) P.gv[be] = s + P.glb[e];
}

// ---------------- MFMA GEMM: Y[g][m][o] = sum_k W[o][k] X[g][m][k] ----------------
// MODE 0: plain (global_load_lds staging, inverse-swizzled source, rule #21)
// MODE 1: +pe epilogue (depthwise 3x3 over CAT[256+o] + residual)
// MODE 2: B from im2col-of-EF with inline sigmoid gate (reg-staged, swizzled ds_write)
struct GemmP {
  const u16* W; const u16* X; float* Y; u16* Yb; float* St;
  const u16* CAT; const float* W9;   // MODE 1
  const float* EF; const float* GA;  // MODE 2
  long long xOff[8];
  int lda, O, K, M, G;
};

template <int BM, int NWO, int WO, int WM, int MODE>
__global__ __launch_bounds__(256) void k_gemm(GemmP P) {
  constexpr int FO = WO / 16, FM = WM / 16;
  __shared__ __align__(16) char lds[16384 + BM * 128];
  const int mt = P.M / BM;
  const int ot = P.O >> 7;
  int bid = blockIdx.x;
  const int g = bid / (mt * ot);
  const int rr = bid % (mt * ot);
  const int ob = (rr / mt) << 7;
  const int mb = (rr % mt) * BM;
  const int t = threadIdx.x, lane = t & 63, wave = t >> 6;
  const int wo = (wave % NWO) * WO, wm = (wave / NWO) * WM;
  const u16* Wp = P.W + (size_t)ob * P.K;
  const u16* Xp = (MODE == 2) ? nullptr : (P.X + P.xOff[g] + (size_t)mb * P.lda);

  float gt = 0.f;
  int bq2304 = 0;
  if constexpr (MODE == 2) {
    bq2304 = (g >> 2) * 2304 + (g & 3) * 576;
    float a = P.GA[g] / sqrtf(73728.0f);
    gt = 1.f / (1.f + __expf(-a));
  }

  f32x4 acc[FO][FM] = {};

  for (int k0 = 0; k0 < P.K; k0 += 64) {
    // A: 128 rows x 64 k = 1024 slots of 16B
#pragma unroll
    for (int i = 0; i < 4; i++) {
      int s = (i * 4 + wave) * 64 + lane;
      int row = s >> 3;
      int kg = (s & 7) ^ (row & 7);
      const u16* src = Wp + (size_t)row * P.K + k0 + kg * 8;
      __builtin_amdgcn_global_load_lds(
          (const __attribute__((address_space(1))) u32*)src,
          (__attribute__((address_space(3))) u32*)(lds + (size_t)(i * 4 + wave) * 1024),
          16, 0, 0);
    }
    if constexpr (MODE != 2) {
#pragma unroll
      for (int i = 0; i < BM * 8 / 256; i++) {
        int s = (i * 4 + wave) * 64 + lane;
        int row = s >> 3;
        int kg = (s & 7) ^ (row & 7);
        const u16* src = Xp + (size_t)row * P.lda + k0 + kg * 8;
        __builtin_amdgcn_global_load_lds(
            (const __attribute__((address_space(1))) u32*)src,
            (__attribute__((address_space(3))) u32*)(lds + 16384 + (size_t)(i * 4 + wave) * 1024),
            16, 0, 0);
      }
    } else {
      // im2col gather: slot s = (row=token, kg); k = kk*128+cc (8 ch of tap kk)
#pragma unroll
      for (int i = 0; i < 2; i++) {
        int s = t + i * 256;
        int row = s >> 3, kg = s & 7;
        int k = k0 + kg * 8;
        int kk = k >> 7, cc = k & 127;
        int n = mb + row;
        int h = n / 24 + kk / 3 - 1, w = n % 24 + kk % 3 - 1;
        u16 pk[8];
        if (h >= 0 && h < 24 && w >= 0 && w < 24) {
          const float* ep = P.EF + ((size_t)(bq2304 + h * 24 + w)) * 128 + cc;
          f32x4 v0 = *(const f32x4*)ep;
          f32x4 v1 = *(const f32x4*)(ep + 4);
#pragma unroll
          for (int j = 0; j < 4; j++) {
            pk[j] = f2bf(v0[j] * gt);
            pk[4 + j] = f2bf(v1[j] * gt);
          }
        } else {
#pragma unroll
          for (int j = 0; j < 8; j++) pk[j] = 0;
        }
        *(uint4*)&lds[16384 + (((row << 3) + (kg ^ (row & 7))) << 4)] = *(uint4*)pk;
      }
    }
    __syncthreads();
#pragma unroll
    for (int kk = 0; kk < 2; kk++) {
      int kgl = kk * 4 + (lane >> 4);
      bf16x8 af[FO], bfm[FM];
#pragma unroll
      for (int fo = 0; fo < FO; fo++) {
        int row = wo + fo * 16 + (lane & 15);
        af[fo] = *(bf16x8*)&lds[((row << 3) + (kgl ^ (row & 7))) << 4];
      }
#pragma unroll
      for (int fm = 0; fm < FM; fm++) {
        int row = wm + fm * 16 + (lane & 15);
        bfm[fm] = *(bf16x8*)&lds[16384 + (((row << 3) + (kgl ^ (row & 7))) << 4)];
      }
#pragma unroll
      for (int fo = 0; fo < FO; fo++)
#pragma unroll
        for (int fm = 0; fm < FM; fm++)
          acc[fo][fm] = __builtin_amdgcn_mfma_f32_16x16x32_bf16(af[fo], bfm[fm], acc[fo][fm], 0, 0, 0);
    }
    __syncthreads();
  }

  size_t ybase = (size_t)g * P.M * P.O;
#pragma unroll
  for (int fo = 0; fo < FO; fo++) {
    int ow = ob + wo + fo * 16 + ((lane >> 4) << 2);
#pragma unroll
    for (int fm = 0; fm < FM; fm++) {
      int m = mb + wm + fm * 16 + (lane & 15);
      f32x4 v = acc[fo][fm];
      if constexpr (MODE == 1) {
        // pe depthwise 3x3 on CAT[ch 256+ow] + residual, fused
        size_t tokc = ((size_t)g * 2304 + m) * 1024 + 256 + ow;
        ushort4 cv = *(const ushort4*)&P.CAT[tokc];
        v[0] += bf2f(cv.x); v[1] += bf2f(cv.y); v[2] += bf2f(cv.z); v[3] += bf2f(cv.w);
        int q_ = m / 576, hw_ = m % 576, h_ = hw_ / 24, w_ = hw_ % 24;
        size_t rowb = ((size_t)g * 2304 + q_ * 576) * 1024 + 256 + ow;
#pragma unroll
        for (int tp = 0; tp < 9; tp++) {
          int hh = h_ + tp / 3 - 1, ww = w_ + tp % 3 - 1;
          if (hh < 0 || hh > 23 || ww < 0 || ww > 23) continue;
          ushort4 tv = *(const ushort4*)&P.CAT[rowb + (size_t)(hh * 24 + ww) * 1024];
          f32x4 wt = *(const f32x4*)&P.W9[tp * 256 + ow];
          v[0] = fmaf(wt[0], bf2f(tv.x), v[0]);
          v[1] = fmaf(wt[1], bf2f(tv.y), v[1]);
          v[2] = fmaf(wt[2], bf2f(tv.z), v[2]);
          v[3] = fmaf(wt[3], bf2f(tv.w), v[3]);
        }
        acc[fo][fm] = v;  // keep St consistent if ever combined
      }
      size_t off = ybase + (size_t)m * P.O + ow;
      if (P.Y) *(f32x4*)&P.Y[off] = v;
      if (P.Yb) {
        ushort4 r;
        r.x = f2bf(v[0]); r.y = f2bf(v[1]); r.z = f2bf(v[2]); r.w = f2bf(v[3]);
        *(ushort4*)&P.Yb[off] = r;
      }
    }
  }

  // fused BN partial sums
  if (P.St) {
#pragma unroll
    for (int fo = 0; fo < FO; fo++) {
      float sv[4], qv[4];
#pragma unroll
      for (int j = 0; j < 4; j++) { sv[j] = 0.f; qv[j] = 0.f; }
#pragma unroll
      for (int fm = 0; fm < FM; fm++)
#pragma unroll
        for (int j = 0; j < 4; j++) {
          float a = acc[fo][fm][j];
          sv[j] += a;
          qv[j] = fmaf(a, a, qv[j]);
        }
#pragma unroll
      for (int j = 0; j < 4; j++) {
#pragma unroll
        for (int mk = 1; mk < 16; mk <<= 1) {
          sv[j] += __shfl_xor(sv[j], mk, 64);
          qv[j] += __shfl_xor(qv[j], mk, 64);
        }
      }
      if ((lane & 15) == 0) {
        int o = ob + wo + fo * 16 + ((lane >> 4) << 2);
#pragma unroll
        for (int j = 0; j < 4; j++) {
          atomicAdd(&P.St[2 * (o + j)], sv[j]);
          atomicAdd(&P.St[2 * (o + j) + 1], qv[j]);
        }
      }
    }
  }
}

// ---------------- BN normalize from raw sums (+bf16 add, relu, opt gate accum) ------------
struct NormP {
  const float* X; const float* st; const u16* AddB;
  u16* Yb; float* Yf; const float* gv; float* gacc;
  long long ybOff[8];
  int ldyb, O, G, M, relu;
  float n;
};
__global__ __launch_bounds__(256) void k_norm(NormP P) {
  int O4 = P.O >> 2;
  long long idx = (long long)blockIdx.x * 256 + threadIdx.x;
  if (idx >= (long long)P.G * P.M * O4) return;
  int c4 = (int)(idx % O4);
  long long gm = idx / O4;
  int m = (int)(gm % P.M);
  int g = (int)(gm / P.M);
  size_t off = (size_t)gm * P.O + c4 * 4;
  f32x4 v = *(const f32x4*)&P.X[off];
  float inv_n = 1.0f / P.n;
#pragma unroll
  for (int j = 0; j < 4; j++) {
    int c = c4 * 4 + j;
    float mean = P.st[2 * c] * inv_n;
    float var = P.st[2 * c + 1] * inv_n - mean * mean;
    v[j] = (v[j] - mean) * rsqrtf(var + 1e-5f);
  }
  if (P.AddB) {
    ushort4 av = *(const ushort4*)(P.AddB + off);
    v[0] += bf2f(av.x); v[1] += bf2f(av.y); v[2] += bf2f(av.z); v[3] += bf2f(av.w);
  }
  if (P.relu) {
#pragma unroll
    for (int j = 0; j < 4; j++) v[j] = fmaxf(v[j], 0.f);
  }
  if (P.Yb) {
    ushort4 r;
    r.x = f2bf(v[0]); r.y = f2bf(v[1]); r.z = f2bf(v[2]); r.w = f2bf(v[3]);
    *(ushort4*)(P.Yb + P.ybOff[g] + (size_t)m * P.ldyb + c4 * 4) = r;
  }
  if (P.Yf) *(f32x4*)&P.Yf[off] = v;
  if (P.gacc) {  // block covers a single (g,q); accumulate e·gv
    float gs = 0.f;
#pragma unroll
    for (int j = 0; j < 4; j++) gs = fmaf(v[j], P.gv[g * 128 + c4 * 4 + j], gs);
#pragma unroll
    for (int mk = 1; mk < 64; mk <<= 1) gs += __shfl_xor(gs, mk, 64);
    __shared__ float t1[4];
    int lane = threadIdx.x & 63, wv = threadIdx.x >> 6;
    if (lane == 0) t1[wv] = gs;
    __syncthreads();
    if (threadIdx.x == 0)
      atomicAdd(&P.gacc[g * 4 + m / 576], t1[0] + t1[1] + t1[2] + t1[3]);
  }
}

// ---------------- final norm + transpose via LDS tile (coalesced both sides) ----------------
__global__ __launch_bounds__(256) void k_normT(const float* X, const float* st, float* out) {
  int bid = blockIdx.x;  // 2 x 72 x 16
  int ot = bid & 15;
  int mt = (bid >> 4) % 72;
  int b = bid / 1152;
  int mb = mt * 32, ob = ot * 32;
  __shared__ float tile[32][33];
  int c = threadIdx.x & 31, r = threadIdx.x >> 5;
#pragma unroll
  for (int i = 0; i < 4; i++) {
    int row = r + i * 8;  // m offset
    tile[row][c] = X[((size_t)b * 2304 + mb + row) * 512 + ob + c];
  }
  __syncthreads();
  float inv_n = 1.0f / 4608.0f;
#pragma unroll
  for (int i = 0; i < 4; i++) {
    int o = ob + r + i * 8;
    float mean = st[2 * o] * inv_n;
    float var = st[2 * o + 1] * inv_n - mean * mean;
    float rs = rsqrtf(var + 1e-5f);
    float v = fmaxf((tile[c][r + i * 8] - mean) * rs, 0.f);
    out[((size_t)(b * 512 + o)) * 2304 + mb + c] = v;
  }
}

// ---------------- MFMA flash attention (no-max softmax; scores tiny) ----------------
__global__ __launch_bounds__(256) void k_attn(const u16* qkv, u16* ao) {
  int bid = blockIdx.x;
  int tq = bid % 3; int u = bid / 3;
  int qd = u & 3; u >>= 2;
  int head = u & 15, b = u >> 4;
  int t = threadIdx.x, lane = t & 63, wv = t >> 6;
  int g = lane >> 4, q = lane & 15;
  size_t tok0 = (size_t)b * 2304 + qd * 576;
  const u16* QKV = qkv + tok0 * 768;

  __shared__ __align__(16) char shm[50176];
  u16* Kl = (u16*)(shm);                       // [576][24]
  u16* VT = (u16*)(shm + 27648);               // [(m>>3)][d][m&7]
  u16* Pl = (u16*)(shm + 46080 + wv * 1024);   // [4][16][8]

  for (int i = t; i < 1152; i += 256) {
    int m = i >> 1, half = i & 1;
    const u16* src = QKV + (size_t)m * 768 + 256 + head * 16 + half * 8;
    u16 tmp[8];
    *(uint4*)tmp = *(const uint4*)src;
    ushort4 lo, hi;
    lo.x = f2bf(bf2f(tmp[0]) * 0.25f); lo.y = f2bf(bf2f(tmp[1]) * 0.25f);
    lo.z = f2bf(bf2f(tmp[2]) * 0.25f); lo.w = f2bf(bf2f(tmp[3]) * 0.25f);
    hi.x = f2bf(bf2f(tmp[4]) * 0.25f); hi.y = f2bf(bf2f(tmp[5]) * 0.25f);
    hi.z = f2bf(bf2f(tmp[6]) * 0.25f); hi.w = f2bf(bf2f(tmp[7]) * 0.25f);
    u16* dst = Kl + m * 24 + half * 8;
    *(ushort4*)dst = lo;
    *(ushort4*)(dst + 4) = hi;
  }
  for (int mm = t; mm < 576; mm += 256) {
    const u16* src = QKV + (size_t)mm * 768 + 512 + head * 16;
    u16 tmp[16];
    *(uint4*)tmp = *(const uint4*)src;
    *(uint4*)(tmp + 8) = *(const uint4*)(src + 8);
    u16* dst = VT + (mm >> 3) * 128 + (mm & 7);
#pragma unroll
    for (int d = 0; d < 16; d++) dst[d * 8] = tmp[d];
  }
  __syncthreads();

#pragma unroll 1
  for (int i = 0; i < 3; i++) {
    int tl = wv * 3 + i;
    int qbase = tq * 192 + tl * 16;
    bf16x8 qf = {};
    if (g < 2)
      qf = *(const bf16x8*)(QKV + (size_t)(qbase + q) * 768 + head * 16 + g * 8);

    f32x4 acc_o = {};
    float ssum = 0.f;

    for (int ch = 0; ch < 18; ch++) {
      int m0 = ch * 32;
      f32x4 s[2];
#pragma unroll
      for (int h = 0; h < 2; h++) {
        bf16x8 kf = {};
        if (g < 2)
          kf = *(const bf16x8*)(Kl + (size_t)(m0 + h * 16 + q) * 24 + g * 8);
        f32x4 z = {};
        s[h] = __builtin_amdgcn_mfma_f32_16x16x32_bf16(kf, qf, z, 0, 0, 0);
      }
#pragma unroll
      for (int h = 0; h < 2; h++) {
        float p0 = __expf(s[h][0]);
        float p1 = __expf(s[h][1]);
        float p2 = __expf(s[h][2]);
        float p3 = __expf(s[h][3]);
        ssum += (p0 + p1) + (p2 + p3);
        ushort4 w;
        w.x = f2bf(p0); w.y = f2bf(p1); w.z = f2bf(p2); w.w = f2bf(p3);
        *(ushort4*)(Pl + ((h * 2 + (g >> 1)) * 16 + q) * 8 + (g & 1) * 4) = w;
      }
      bf16x8 va = *(const bf16x8*)(VT + ((m0 >> 3) + g) * 128 + q * 8);
      bf16x8 pa = *(const bf16x8*)(Pl + (g * 16 + q) * 8);
      acc_o = __builtin_amdgcn_mfma_f32_16x16x32_bf16(va, pa, acc_o, 0, 0, 0);
    }

    ssum += __shfl_xor(ssum, 16, 64);
    ssum += __shfl_xor(ssum, 32, 64);
    float inv = 1.f / ssum;
    u16* op = ao + (tok0 + qbase + q) * 256 + head * 16 + g * 4;
    ushort4 r;
    r.x = f2bf(acc_o[0] * inv);
    r.y = f2bf(acc_o[1] * inv);
    r.z = f2bf(acc_o[2] * inv);
    r.w = f2bf(acc_o[3] * inv);
    *(ushort4*)op = r;
  }
}

// ---------------- host ----------------
extern "C" void kernel_launch(void* const* d_in, const int* in_sizes, int n_in,
                              void* d_out, int out_size, void* d_ws, size_t ws_size,
                              hipStream_t stream) {
  if (ws_size < WS_TOTAL) return;
  char* ws = (char*)d_ws;
  u16* WB = (u16*)(ws + OB_WBF);
  float* WPE = (float*)(ws + OB_WPE);
  float* STB = (float*)(ws + OB_ST);
  float* GV = (float*)(ws + OB_GV);
  float* GACC = (float*)(ws + OB_GACC);
  u16* CATB = (u16*)(ws + OB_CAT);
  float* YA = (float*)(ws + OB_YA);
  u16* XBF = (u16*)(ws + OB_U1);
  u16* QKVB = (u16*)(ws + OB_U2);
  float* EF = (float*)(ws + OB_U2 + 10616832);
  u16* HB = (u16*)(ws + OB_U3);
  u16* AOB = (u16*)(ws + OB_AOB);
  u16* A1B = (u16*)(ws + OB_A1B);
  float* out = (float*)d_out;

  // zero stat sums + GV + GACC
  hipMemsetAsync(ws + OB_ST, 0, OB_CAT - OB_ST, stream);

  {  // head: wprep + xpose + guide
    HeadP p;
    const int mi[8] = {2, 4, 6, 10, 12, 14, 18, 20};
    const int sz[8] = {262144, 196608, 65536, 131072, 131072, 32768, 294912, 524288};
    int c = 0;
    for (int i = 0; i < 8; i++) {
      p.m[i] = (const float*)d_in[mi[i]];
      p.p[i] = (const float*)d_in[mi[i] + 1];
      p.cum[i] = c;
      c += sz[i];
    }
    p.cum[8] = c;
    p.wout = WB;
    p.pem = (const float*)d_in[8];
    p.pep = (const float*)d_in[9];
    p.peout = WPE;
    p.x = (const float*)d_in[0];
    p.xb = XBF;
    p.guide = (const float*)d_in[1];
    p.glw = (const float*)d_in[16];
    p.glb = (const float*)d_in[17];
    p.gv = GV;
    p.nwp = (c + 255) / 256;  // 6400
    int grid = p.nwp + 2304 + 64;
    k_head<<<grid, 256, 0, stream>>>(p);
  }

  auto gemm = [&](int mode, size_t wOff, int O, int K, int M, int G,
                  const u16* X, long long xs, long long xadd, int lda,
                  float* Y, u16* Yb, int si) {
    GemmP p;
    p.W = WB + wOff; p.X = X; p.Y = Y; p.Yb = Yb;
    p.St = (si >= 0) ? (STB + si * 1024) : nullptr;
    p.CAT = CATB; p.W9 = WPE; p.EF = EF; p.GA = GACC;
    p.lda = lda; p.O = O; p.K = K; p.M = M; p.G = G;
    for (int g = 0; g < 8; g++) p.xOff[g] = (long long)(g < G ? g : 0) * xs + xadd;
    int grid = G * (O / 128) * (M / 64);
    if (mode == 0)
      k_gemm<64, 4, 32, 64, 0><<<grid, 256, 0, stream>>>(p);
    else if (mode == 1)
      k_gemm<64, 4, 32, 64, 1><<<grid, 256, 0, stream>>>(p);
    else
      k_gemm<64, 4, 32, 64, 2><<<grid, 256, 0, stream>>>(p);
  };
  auto norm = [&](const float* X, int si, int O, int G, int M, const u16* AddB,
                  u16* Yb, int ldyb, const long long* ybOff, float* Yf, int relu,
                  const float* gv, float* gacc) {
    NormP p;
    p.X = X; p.st = STB + si * 1024; p.AddB = AddB; p.Yb = Yb; p.Yf = Yf;
    p.gv = gv; p.gacc = gacc;
    p.ldyb = ldyb; p.O = O; p.G = G; p.M = M; p.relu = relu;
    p.n = (float)(G * M);
    for (int g = 0; g < 8; g++) p.ybOff[g] = ybOff ? ybOff[(g < G) ? g : 0] : 0;
    long long total = (long long)G * M * (O / 4);
    k_norm<<<(int)((total + 255) / 256), 256, 0, stream>>>(p);
  };

  // cv1 -> bn relu -> cat[0:512]
  gemm(0, 0, 512, 512, 2304, 2, XBF, 2304LL * 512, 0, 512, YA, nullptr, 0);
  { long long yo[2] = {0, 2304LL * 1024};
    norm(YA, 0, 512, 2, 2304, nullptr, CATB, 1024, yo, nullptr, 1, nullptr, nullptr); }

  // qkv (bf16 only)
  gemm(0, 262144, 768, 256, 2304, 2, CATB, 2304LL * 1024, 256, 1024, nullptr, QKVB, -1);
  // MFMA flash attention
  k_attn<<<384, 256, 0, stream>>>(QKVB, AOB);
  // aproj + fused pe + residual -> a1 bf16
  gemm(1, 458752, 256, 256, 2304, 2, AOB, 2304LL * 256, 0, 256, nullptr, A1B, -1);

  // ffn1 -> bn relu -> hb
  gemm(0, 524288, 512, 256, 2304, 2, A1B, 2304LL * 256, 0, 256, YA, nullptr, 1);
  { long long yo[2] = {0, 2304LL * 512};
    norm(YA, 1, 512, 2, 2304, nullptr, HB, 512, yo, nullptr, 1, nullptr, nullptr); }

  // ffn2 -> bn -> +a1(bf16) -> cat[512:768]
  gemm(0, 655360, 256, 512, 2304, 2, HB, 2304LL * 512, 0, 512, YA, nullptr, 2);
  { long long yo[2] = {512, 2304LL * 1024 + 512};
    norm(YA, 2, 256, 2, 2304, A1B, CATB, 1024, yo, nullptr, 0, nullptr, nullptr); }

  // ec -> bn relu -> ef (f32) + fused gate partials
  gemm(0, 786432, 128, 256, 2304, 2, CATB, 2304LL * 1024, 512, 1024, YA, nullptr, 3);
  norm(YA, 3, 128, 2, 2304, nullptr, nullptr, 0, nullptr, EF, 1, GV, GACC);

  // mproj (fused im2col + sigmoid gate) -> bn relu -> cat[768:1024]
  gemm(2, 819200, 256, 1152, 576, 8, nullptr, 0, 0, 0, YA, nullptr, 4);
  { long long yo[8];
    for (int g = 0; g < 8; g++)
      yo[g] = (long long)(g >> 2) * 2304 * 1024 + (long long)(g & 3) * 576 * 1024 + 768;
    norm(YA, 4, 256, 8, 576, nullptr, CATB, 1024, yo, nullptr, 1, nullptr, nullptr); }

  // cv2 -> bn relu -> out (LDS-transposed)
  gemm(0, 1114112, 512, 1024, 2304, 2, CATB, 2304LL * 1024, 0, 1024, YA, nullptr, 5);
  k_normT<<<2304, 256, 0, stream>>>(YA, STB + 5 * 1024, out);
}

// Round 8
// 256.395 us; speedup vs baseline: 1.1498x; 1.0649x over previous
//
#include <hip/hip_runtime.h>
#include <math.h>

typedef __bf16 bf16x8 __attribute__((ext_vector_type(8)));
typedef float f32x4 __attribute__((ext_vector_type(4)));
typedef unsigned short u16;
typedef unsigned int u32;

__device__ __forceinline__ u16 f2bf(float f) {
  u32 u = __float_as_uint(f);
  u32 r = u + 0x7FFF + ((u >> 16) & 1);
  return (u16)(r >> 16);
}
__device__ __forceinline__ float bf2f(u16 h) { return __uint_as_float(((u32)h) << 16); }

// ---------------- arena (byte offsets) ----------------
static constexpr size_t OB_WBF = 0;                       // 1,638,400 u16
static constexpr size_t OB_WPE = 3276800;                 // 2304 f32 ([9][256] tap-major)
static constexpr size_t OB_ST  = 3286016;                 // 6 x 4096B stat sums
static constexpr size_t OB_GV  = 3310592;                 // 256 f32
static constexpr size_t OB_GACC= 3311616;                 // 8 f32 gate accum
static constexpr size_t OB_CAT = 3311872;                 // bf16 [2][2304][1024]
static constexpr size_t OB_YA  = OB_CAT + 9437184;        // f32 gemm out (max 9.4MB)
static constexpr size_t OB_U1  = OB_YA + 9437184;         // xbf16 (4.7MB)
static constexpr size_t OB_U2  = OB_U1 + 4718592;         // qkv bf16 7.1MB ; +EF f32 at +10616832
static constexpr size_t OB_U3  = OB_U2 + 14155776;        // hb bf16 (4.7MB)
static constexpr size_t OB_AOB = OB_U3 + 4718592;         // attn out bf16 (2.36MB)
static constexpr size_t OB_A1B = OB_AOB + 2359296;        // a1 bf16 (2.36MB)
static constexpr size_t WS_TOTAL = OB_A1B + 2359296;      // ~50.5MB

// ---------------- head: wprep + x-transpose + guide linear, range-split ----------------
struct HeadP {
  const float* m[8]; const float* p[8]; u16* wout;
  const float* pem; const float* pep; float* peout;
  const float* x; u16* xb;
  const float* guide; const float* glw; const float* glb; float* gv;
  int cum[9]; int nwp;
};
__global__ __launch_bounds__(256) void k_head(HeadP P) {
  int bid = blockIdx.x;
  if (bid < P.nwp) {  // weight prep: w = m*cos(p) -> bf16 (mproj tap-major remap)
    int i = bid * 256 + threadIdx.x;
    if (i < 2304) {  // pe weights transposed [tap][256]
      int tap = i >> 8, c = i & 255;
      P.peout[i] = P.pem[c * 9 + tap] * cosf(P.pep[c * 9 + tap]);
    }
    if (i >= P.cum[8]) return;
    int s = 0;
    while (s < 7 && i >= P.cum[s + 1]) s++;
    int j = i - P.cum[s];
    int src = j;
    if (s == 6) {  // mproj: out[o][kk*128+cc] <- in[(o*128+cc)*9+kk]
      int o = j / 1152, r = j % 1152, kk = r >> 7, cc = r & 127;
      src = (o * 128 + cc) * 9 + kk;
    }
    P.wout[i] = f2bf(P.m[s][src] * cosf(P.p[s][src]));
    return;
  }
  bid -= P.nwp;
  if (bid < 2304) {  // x transpose: [b][c][q][hw] f32 -> [b][q*576+hw][c] bf16
    int mt = bid % 18; bid /= 18;
    int ct = bid % 16; bid /= 16;
    int q = bid & 3, b = bid >> 2;
    __shared__ float tile[32][33];
    int tj = threadIdx.x & 31, ti = threadIdx.x >> 5;
    const float* xp = P.x + (((size_t)(b * 512 + ct * 32) * 4 + q) * 576) + mt * 32;
#pragma unroll
    for (int ii = 0; ii < 4; ii++)
      tile[ti + ii * 8][tj] = xp[(size_t)(ti + ii * 8) * 4 * 576 + tj];
    __syncthreads();
    u16* yp = P.xb + ((size_t)b * 2304 + q * 576 + mt * 32) * 512 + ct * 32;
#pragma unroll
    for (int mm = 0; mm < 4; mm++)
      yp[(size_t)(mm * 8 + ti) * 512 + tj] = f2bf(tile[tj][mm * 8 + ti]);
    return;
  }
  bid -= 2304;  // guide: 64 blocks x 4 waves, one (b,e) per wave
  int wv = threadIdx.x >> 6, lane = threadIdx.x & 63;
  int be = bid * 4 + wv;
  int b = be >> 7, e = be & 127;
  const float* gr = P.guide + b * 512;
  const float* wr = P.glw + e * 512;
  float s = 0.f;
  for (int c = lane; c < 512; c += 64) s = fmaf(gr[c], wr[c], s);
#pragma unroll
  for (int off = 32; off > 0; off >>= 1) s += __shfl_down(s, off, 64);
  if (lane == 0) P.gv[be] = s + P.glb[e];
}

// ---------------- MFMA GEMM, 2-phase prefetch (T3 minimum recipe) ----------------
// MODE 0: plain; MODE 1: +pe epilogue; MODE 2: B = im2col(EF)*sigmoid gate (T14 split)
struct GemmP {
  const u16* W; const u16* X; float* Y; u16* Yb; float* St;
  const u16* CAT; const float* W9;   // MODE 1
  const float* EF; const float* GA;  // MODE 2
  long long xOff[8];
  int lda, O, K, M, G;
};

template <int BM, int NWO, int WO, int WM, int MODE>
__global__ __launch_bounds__(256) void k_gemm(GemmP P) {
  constexpr int FO = WO / 16, FM = WM / 16;
  constexpr int ABYTES = 16384, BBYTES = BM * 128;
  __shared__ __align__(16) char lds[2 * ABYTES + 2 * BBYTES];
  const int mt = P.M / BM;
  const int ot = P.O >> 7;
  int bid = blockIdx.x;
  const int g = bid / (mt * ot);
  const int rr = bid % (mt * ot);
  const int ob = (rr / mt) << 7;
  const int mb = (rr % mt) * BM;
  const int t = threadIdx.x, lane = t & 63, wave = t >> 6;
  const int wo = (wave % NWO) * WO, wm = (wave / NWO) * WM;
  const u16* Wp = P.W + (size_t)ob * P.K;
  const u16* Xp = (MODE == 2) ? nullptr : (P.X + P.xOff[g] + (size_t)mb * P.lda);

  float gt = 0.f;
  int bq2304 = 0;
  if constexpr (MODE == 2) {
    bq2304 = (g >> 2) * 2304 + (g & 3) * 576;
    float a = P.GA[g] / sqrtf(73728.0f);
    gt = 1.f / (1.f + __expf(-a));
  }

  f32x4 acc[FO][FM] = {};
  float vreg[2][8];

  auto stageA = [&](int tb, int k0) {
#pragma unroll
    for (int i = 0; i < 4; i++) {
      int s = (i * 4 + wave) * 64 + lane;
      int row = s >> 3;
      int kg = (s & 7) ^ (row & 7);
      const u16* src = Wp + (size_t)row * P.K + k0 + kg * 8;
      __builtin_amdgcn_global_load_lds(
          (const __attribute__((address_space(1))) u32*)src,
          (__attribute__((address_space(3))) u32*)(lds + tb * ABYTES + (size_t)(i * 4 + wave) * 1024),
          16, 0, 0);
    }
  };
  auto stageB = [&](int tb, int k0) {
#pragma unroll
    for (int i = 0; i < BM * 8 / 256; i++) {
      int s = (i * 4 + wave) * 64 + lane;
      int row = s >> 3;
      int kg = (s & 7) ^ (row & 7);
      const u16* src = Xp + (size_t)row * P.lda + k0 + kg * 8;
      __builtin_amdgcn_global_load_lds(
          (const __attribute__((address_space(1))) u32*)src,
          (__attribute__((address_space(3))) u32*)(lds + 2 * ABYTES + tb * BBYTES +
                                                   (size_t)(i * 4 + wave) * 1024),
          16, 0, 0);
    }
  };
  auto loadEF = [&](int k0) {
#pragma unroll
    for (int i = 0; i < 2; i++) {
      int s = t + i * 256;
      int row = s >> 3, kg = s & 7;
      int k = k0 + kg * 8;
      int kk = k >> 7, cc = k & 127;
      int n = mb + row;
      int h = n / 24 + kk / 3 - 1, w = n % 24 + kk % 3 - 1;
      if (h >= 0 && h < 24 && w >= 0 && w < 24) {
        const float* ep = P.EF + ((size_t)(bq2304 + h * 24 + w)) * 128 + cc;
        f32x4 v0 = *(const f32x4*)ep;
        f32x4 v1 = *(const f32x4*)(ep + 4);
#pragma unroll
        for (int j = 0; j < 4; j++) { vreg[i][j] = v0[j]; vreg[i][4 + j] = v1[j]; }
      } else {
#pragma unroll
        for (int j = 0; j < 8; j++) vreg[i][j] = 0.f;
      }
    }
  };
  auto writeB = [&](int tb) {
#pragma unroll
    for (int i = 0; i < 2; i++) {
      int s = t + i * 256;
      int row = s >> 3, kg = s & 7;
      u16 pk[8];
#pragma unroll
      for (int j = 0; j < 8; j++) pk[j] = f2bf(vreg[i][j] * gt);
      *(uint4*)&lds[2 * ABYTES + tb * BBYTES + (((row << 3) + (kg ^ (row & 7))) << 4)] =
          *(uint4*)pk;
    }
  };

  const int nt = P.K >> 6;
  // prologue: stage tile 0
  stageA(0, 0);
  if constexpr (MODE != 2) {
    stageB(0, 0);
  } else {
    loadEF(0);
    writeB(0);
  }
  __syncthreads();

  for (int tt = 0; tt < nt; tt++) {
    const int cur = tt & 1, nxt = cur ^ 1;
    const bool more = (tt + 1) < nt;
    if (more) {  // issue next tile's loads BEFORE compute (latency hides under MFMA)
      stageA(nxt, (tt + 1) << 6);
      if constexpr (MODE != 2) stageB(nxt, (tt + 1) << 6);
      else loadEF((tt + 1) << 6);
    }
    const char* bA = lds + cur * ABYTES;
    const char* bB = lds + 2 * ABYTES + cur * BBYTES;
#pragma unroll
    for (int kk = 0; kk < 2; kk++) {
      int kgl = kk * 4 + (lane >> 4);
      bf16x8 af[FO], bfm[FM];
#pragma unroll
      for (int fo = 0; fo < FO; fo++) {
        int row = wo + fo * 16 + (lane & 15);
        af[fo] = *(bf16x8*)&bA[((row << 3) + (kgl ^ (row & 7))) << 4];
      }
#pragma unroll
      for (int fm = 0; fm < FM; fm++) {
        int row = wm + fm * 16 + (lane & 15);
        bfm[fm] = *(bf16x8*)&bB[((row << 3) + (kgl ^ (row & 7))) << 4];
      }
#pragma unroll
      for (int fo = 0; fo < FO; fo++)
#pragma unroll
        for (int fm = 0; fm < FM; fm++)
          acc[fo][fm] = __builtin_amdgcn_mfma_f32_16x16x32_bf16(af[fo], bfm[fm], acc[fo][fm], 0, 0, 0);
    }
    if (more) {
      if constexpr (MODE == 2) writeB(nxt);  // write-late: loads had compute to fly
      __syncthreads();
    }
  }

  size_t ybase = (size_t)g * P.M * P.O;
#pragma unroll
  for (int fo = 0; fo < FO; fo++) {
    int ow = ob + wo + fo * 16 + ((lane >> 4) << 2);
#pragma unroll
    for (int fm = 0; fm < FM; fm++) {
      int m = mb + wm + fm * 16 + (lane & 15);
      f32x4 v = acc[fo][fm];
      if constexpr (MODE == 1) {
        // pe depthwise 3x3 on CAT[ch 256+ow] + residual, fused
        size_t tokc = ((size_t)g * 2304 + m) * 1024 + 256 + ow;
        ushort4 cv = *(const ushort4*)&P.CAT[tokc];
        v[0] += bf2f(cv.x); v[1] += bf2f(cv.y); v[2] += bf2f(cv.z); v[3] += bf2f(cv.w);
        int q_ = m / 576, hw_ = m % 576, h_ = hw_ / 24, w_ = hw_ % 24;
        size_t rowb = ((size_t)g * 2304 + q_ * 576) * 1024 + 256 + ow;
#pragma unroll
        for (int tp = 0; tp < 9; tp++) {
          int hh = h_ + tp / 3 - 1, ww = w_ + tp % 3 - 1;
          if (hh < 0 || hh > 23 || ww < 0 || ww > 23) continue;
          ushort4 tv = *(const ushort4*)&P.CAT[rowb + (size_t)(hh * 24 + ww) * 1024];
          f32x4 wt = *(const f32x4*)&P.W9[tp * 256 + ow];
          v[0] = fmaf(wt[0], bf2f(tv.x), v[0]);
          v[1] = fmaf(wt[1], bf2f(tv.y), v[1]);
          v[2] = fmaf(wt[2], bf2f(tv.z), v[2]);
          v[3] = fmaf(wt[3], bf2f(tv.w), v[3]);
        }
        acc[fo][fm] = v;
      }
      size_t off = ybase + (size_t)m * P.O + ow;
      if (P.Y) *(f32x4*)&P.Y[off] = v;
      if (P.Yb) {
        ushort4 r;
        r.x = f2bf(v[0]); r.y = f2bf(v[1]); r.z = f2bf(v[2]); r.w = f2bf(v[3]);
        *(ushort4*)&P.Yb[off] = r;
      }
    }
  }

  // fused BN partial sums
  if (P.St) {
#pragma unroll
    for (int fo = 0; fo < FO; fo++) {
      float sv[4], qv[4];
#pragma unroll
      for (int j = 0; j < 4; j++) { sv[j] = 0.f; qv[j] = 0.f; }
#pragma unroll
      for (int fm = 0; fm < FM; fm++)
#pragma unroll
        for (int j = 0; j < 4; j++) {
          float a = acc[fo][fm][j];
          sv[j] += a;
          qv[j] = fmaf(a, a, qv[j]);
        }
#pragma unroll
      for (int j = 0; j < 4; j++) {
#pragma unroll
        for (int mk = 1; mk < 16; mk <<= 1) {
          sv[j] += __shfl_xor(sv[j], mk, 64);
          qv[j] += __shfl_xor(qv[j], mk, 64);
        }
      }
      if ((lane & 15) == 0) {
        int o = ob + wo + fo * 16 + ((lane >> 4) << 2);
#pragma unroll
        for (int j = 0; j < 4; j++) {
          atomicAdd(&P.St[2 * (o + j)], sv[j]);
          atomicAdd(&P.St[2 * (o + j) + 1], qv[j]);
        }
      }
    }
  }
}

// ---------------- BN normalize from raw sums (+bf16 add, relu, opt gate accum) ------------
struct NormP {
  const float* X; const float* st; const u16* AddB;
  u16* Yb; float* Yf; const float* gv; float* gacc;
  long long ybOff[8];
  int ldyb, O, G, M, relu;
  float n;
};
__global__ __launch_bounds__(256) void k_norm(NormP P) {
  int O4 = P.O >> 2;
  long long idx = (long long)blockIdx.x * 256 + threadIdx.x;
  if (idx >= (long long)P.G * P.M * O4) return;
  int c4 = (int)(idx % O4);
  long long gm = idx / O4;
  int m = (int)(gm % P.M);
  int g = (int)(gm / P.M);
  size_t off = (size_t)gm * P.O + c4 * 4;
  f32x4 v = *(const f32x4*)&P.X[off];
  float inv_n = 1.0f / P.n;
#pragma unroll
  for (int j = 0; j < 4; j++) {
    int c = c4 * 4 + j;
    float mean = P.st[2 * c] * inv_n;
    float var = P.st[2 * c + 1] * inv_n - mean * mean;
    v[j] = (v[j] - mean) * rsqrtf(var + 1e-5f);
  }
  if (P.AddB) {
    ushort4 av = *(const ushort4*)(P.AddB + off);
    v[0] += bf2f(av.x); v[1] += bf2f(av.y); v[2] += bf2f(av.z); v[3] += bf2f(av.w);
  }
  if (P.relu) {
#pragma unroll
    for (int j = 0; j < 4; j++) v[j] = fmaxf(v[j], 0.f);
  }
  if (P.Yb) {
    ushort4 r;
    r.x = f2bf(v[0]); r.y = f2bf(v[1]); r.z = f2bf(v[2]); r.w = f2bf(v[3]);
    *(ushort4*)(P.Yb + P.ybOff[g] + (size_t)m * P.ldyb + c4 * 4) = r;
  }
  if (P.Yf) *(f32x4*)&P.Yf[off] = v;
  if (P.gacc) {  // block covers a single (g,q); accumulate e·gv
    float gs = 0.f;
#pragma unroll
    for (int j = 0; j < 4; j++) gs = fmaf(v[j], P.gv[g * 128 + c4 * 4 + j], gs);
#pragma unroll
    for (int mk = 1; mk < 64; mk <<= 1) gs += __shfl_xor(gs, mk, 64);
    __shared__ float t1[4];
    int lane = threadIdx.x & 63, wv = threadIdx.x >> 6;
    if (lane == 0) t1[wv] = gs;
    __syncthreads();
    if (threadIdx.x == 0)
      atomicAdd(&P.gacc[g * 4 + m / 576], t1[0] + t1[1] + t1[2] + t1[3]);
  }
}

// ---------------- final norm + transpose via LDS tile (coalesced both sides) ----------------
__global__ __launch_bounds__(256) void k_normT(const float* X, const float* st, float* out) {
  int bid = blockIdx.x;  // 2 x 72 x 16
  int ot = bid & 15;
  int mt = (bid >> 4) % 72;
  int b = bid / 1152;
  int mb = mt * 32, ob = ot * 32;
  __shared__ float tile[32][33];
  int c = threadIdx.x & 31, r = threadIdx.x >> 5;
#pragma unroll
  for (int i = 0; i < 4; i++) {
    int row = r + i * 8;  // m offset
    tile[row][c] = X[((size_t)b * 2304 + mb + row) * 512 + ob + c];
  }
  __syncthreads();
  float inv_n = 1.0f / 4608.0f;
#pragma unroll
  for (int i = 0; i < 4; i++) {
    int o = ob + r + i * 8;
    float mean = st[2 * o] * inv_n;
    float var = st[2 * o + 1] * inv_n - mean * mean;
    float rs = rsqrtf(var + 1e-5f);
    float v = fmaxf((tile[c][r + i * 8] - mean) * rs, 0.f);
    out[((size_t)(b * 512 + o)) * 2304 + mb + c] = v;
  }
}

// ---------------- MFMA flash attention (no-max softmax; scores tiny) ----------------
__global__ __launch_bounds__(256) void k_attn(const u16* qkv, u16* ao) {
  int bid = blockIdx.x;
  int tq = bid % 3; int u = bid / 3;
  int qd = u & 3; u >>= 2;
  int head = u & 15, b = u >> 4;
  int t = threadIdx.x, lane = t & 63, wv = t >> 6;
  int g = lane >> 4, q = lane & 15;
  size_t tok0 = (size_t)b * 2304 + qd * 576;
  const u16* QKV = qkv + tok0 * 768;

  __shared__ __align__(16) char shm[50176];
  u16* Kl = (u16*)(shm);                       // [576][24]
  u16* VT = (u16*)(shm + 27648);               // [(m>>3)][d][m&7]
  u16* Pl = (u16*)(shm + 46080 + wv * 1024);   // [4][16][8]

  for (int i = t; i < 1152; i += 256) {
    int m = i >> 1, half = i & 1;
    const u16* src = QKV + (size_t)m * 768 + 256 + head * 16 + half * 8;
    u16 tmp[8];
    *(uint4*)tmp = *(const uint4*)src;
    ushort4 lo, hi;
    lo.x = f2bf(bf2f(tmp[0]) * 0.25f); lo.y = f2bf(bf2f(tmp[1]) * 0.25f);
    lo.z = f2bf(bf2f(tmp[2]) * 0.25f); lo.w = f2bf(bf2f(tmp[3]) * 0.25f);
    hi.x = f2bf(bf2f(tmp[4]) * 0.25f); hi.y = f2bf(bf2f(tmp[5]) * 0.25f);
    hi.z = f2bf(bf2f(tmp[6]) * 0.25f); hi.w = f2bf(bf2f(tmp[7]) * 0.25f);
    u16* dst = Kl + m * 24 + half * 8;
    *(ushort4*)dst = lo;
    *(ushort4*)(dst + 4) = hi;
  }
  for (int mm = t; mm < 576; mm += 256) {
    const u16* src = QKV + (size_t)mm * 768 + 512 + head * 16;
    u16 tmp[16];
    *(uint4*)tmp = *(const uint4*)src;
    *(uint4*)(tmp + 8) = *(const uint4*)(src + 8);
    u16* dst = VT + (mm >> 3) * 128 + (mm & 7);
#pragma unroll
    for (int d = 0; d < 16; d++) dst[d * 8] = tmp[d];
  }
  __syncthreads();

#pragma unroll 1
  for (int i = 0; i < 3; i++) {
    int tl = wv * 3 + i;
    int qbase = tq * 192 + tl * 16;
    bf16x8 qf = {};
    if (g < 2)
      qf = *(const bf16x8*)(QKV + (size_t)(qbase + q) * 768 + head * 16 + g * 8);

    f32x4 acc_o = {};
    float ssum = 0.f;

    for (int ch = 0; ch < 18; ch++) {
      int m0 = ch * 32;
      f32x4 s[2];
#pragma unroll
      for (int h = 0; h < 2; h++) {
        bf16x8 kf = {};
        if (g < 2)
          kf = *(const bf16x8*)(Kl + (size_t)(m0 + h * 16 + q) * 24 + g * 8);
        f32x4 z = {};
        s[h] = __builtin_amdgcn_mfma_f32_16x16x32_bf16(kf, qf, z, 0, 0, 0);
      }
#pragma unroll
      for (int h = 0; h < 2; h++) {
        float p0 = __expf(s[h][0]);
        float p1 = __expf(s[h][1]);
        float p2 = __expf(s[h][2]);
        float p3 = __expf(s[h][3]);
        ssum += (p0 + p1) + (p2 + p3);
        ushort4 w;
        w.x = f2bf(p0); w.y = f2bf(p1); w.z = f2bf(p2); w.w = f2bf(p3);
        *(ushort4*)(Pl + ((h * 2 + (g >> 1)) * 16 + q) * 8 + (g & 1) * 4) = w;
      }
      bf16x8 va = *(const bf16x8*)(VT + ((m0 >> 3) + g) * 128 + q * 8);
      bf16x8 pa = *(const bf16x8*)(Pl + (g * 16 + q) * 8);
      acc_o = __builtin_amdgcn_mfma_f32_16x16x32_bf16(va, pa, acc_o, 0, 0, 0);
    }

    ssum += __shfl_xor(ssum, 16, 64);
    ssum += __shfl_xor(ssum, 32, 64);
    float inv = 1.f / ssum;
    u16* op = ao + (tok0 + qbase + q) * 256 + head * 16 + g * 4;
    ushort4 r;
    r.x = f2bf(acc_o[0] * inv);
    r.y = f2bf(acc_o[1] * inv);
    r.z = f2bf(acc_o[2] * inv);
    r.w = f2bf(acc_o[3] * inv);
    *(ushort4*)op = r;
  }
}

// ---------------- host ----------------
extern "C" void kernel_launch(void* const* d_in, const int* in_sizes, int n_in,
                              void* d_out, int out_size, void* d_ws, size_t ws_size,
                              hipStream_t stream) {
  if (ws_size < WS_TOTAL) return;
  char* ws = (char*)d_ws;
  u16* WB = (u16*)(ws + OB_WBF);
  float* WPE = (float*)(ws + OB_WPE);
  float* STB = (float*)(ws + OB_ST);
  float* GV = (float*)(ws + OB_GV);
  float* GACC = (float*)(ws + OB_GACC);
  u16* CATB = (u16*)(ws + OB_CAT);
  float* YA = (float*)(ws + OB_YA);
  u16* XBF = (u16*)(ws + OB_U1);
  u16* QKVB = (u16*)(ws + OB_U2);
  float* EF = (float*)(ws + OB_U2 + 10616832);
  u16* HB = (u16*)(ws + OB_U3);
  u16* AOB = (u16*)(ws + OB_AOB);
  u16* A1B = (u16*)(ws + OB_A1B);
  float* out = (float*)d_out;

  // zero stat sums + GV + GACC
  hipMemsetAsync(ws + OB_ST, 0, OB_CAT - OB_ST, stream);

  {  // head: wprep + xpose + guide
    HeadP p;
    const int mi[8] = {2, 4, 6, 10, 12, 14, 18, 20};
    const int sz[8] = {262144, 196608, 65536, 131072, 131072, 32768, 294912, 524288};
    int c = 0;
    for (int i = 0; i < 8; i++) {
      p.m[i] = (const float*)d_in[mi[i]];
      p.p[i] = (const float*)d_in[mi[i] + 1];
      p.cum[i] = c;
      c += sz[i];
    }
    p.cum[8] = c;
    p.wout = WB;
    p.pem = (const float*)d_in[8];
    p.pep = (const float*)d_in[9];
    p.peout = WPE;
    p.x = (const float*)d_in[0];
    p.xb = XBF;
    p.guide = (const float*)d_in[1];
    p.glw = (const float*)d_in[16];
    p.glb = (const float*)d_in[17];
    p.gv = GV;
    p.nwp = (c + 255) / 256;  // 6400
    int grid = p.nwp + 2304 + 64;
    k_head<<<grid, 256, 0, stream>>>(p);
  }

  auto gemm = [&](int mode, size_t wOff, int O, int K, int M, int G,
                  const u16* X, long long xs, long long xadd, int lda,
                  float* Y, u16* Yb, int si) {
    GemmP p;
    p.W = WB + wOff; p.X = X; p.Y = Y; p.Yb = Yb;
    p.St = (si >= 0) ? (STB + si * 1024) : nullptr;
    p.CAT = CATB; p.W9 = WPE; p.EF = EF; p.GA = GACC;
    p.lda = lda; p.O = O; p.K = K; p.M = M; p.G = G;
    for (int g = 0; g < 8; g++) p.xOff[g] = (long long)(g < G ? g : 0) * xs + xadd;
    int grid = G * (O / 128) * (M / 64);
    if (mode == 0)
      k_gemm<64, 4, 32, 64, 0><<<grid, 256, 0, stream>>>(p);
    else if (mode == 1)
      k_gemm<64, 4, 32, 64, 1><<<grid, 256, 0, stream>>>(p);
    else
      k_gemm<64, 4, 32, 64, 2><<<grid, 256, 0, stream>>>(p);
  };
  auto norm = [&](const float* X, int si, int O, int G, int M, const u16* AddB,
                  u16* Yb, int ldyb, const long long* ybOff, float* Yf, int relu,
                  const float* gv, float* gacc) {
    NormP p;
    p.X = X; p.st = STB + si * 1024; p.AddB = AddB; p.Yb = Yb; p.Yf = Yf;
    p.gv = gv; p.gacc = gacc;
    p.ldyb = ldyb; p.O = O; p.G = G; p.M = M; p.relu = relu;
    p.n = (float)(G * M);
    for (int g = 0; g < 8; g++) p.ybOff[g] = ybOff ? ybOff[(g < G) ? g : 0] : 0;
    long long total = (long long)G * M * (O / 4);
    k_norm<<<(int)((total + 255) / 256), 256, 0, stream>>>(p);
  };

  // cv1 -> bn relu -> cat[0:512]
  gemm(0, 0, 512, 512, 2304, 2, XBF, 2304LL * 512, 0, 512, YA, nullptr, 0);
  { long long yo[2] = {0, 2304LL * 1024};
    norm(YA, 0, 512, 2, 2304, nullptr, CATB, 1024, yo, nullptr, 1, nullptr, nullptr); }

  // qkv (bf16 only)
  gemm(0, 262144, 768, 256, 2304, 2, CATB, 2304LL * 1024, 256, 1024, nullptr, QKVB, -1);
  // MFMA flash attention
  k_attn<<<384, 256, 0, stream>>>(QKVB, AOB);
  // aproj + fused pe + residual -> a1 bf16
  gemm(1, 458752, 256, 256, 2304, 2, AOB, 2304LL * 256, 0, 256, nullptr, A1B, -1);

  // ffn1 -> bn relu -> hb
  gemm(0, 524288, 512, 256, 2304, 2, A1B, 2304LL * 256, 0, 256, YA, nullptr, 1);
  { long long yo[2] = {0, 2304LL * 512};
    norm(YA, 1, 512, 2, 2304, nullptr, HB, 512, yo, nullptr, 1, nullptr, nullptr); }

  // ffn2 -> bn -> +a1(bf16) -> cat[512:768]
  gemm(0, 655360, 256, 512, 2304, 2, HB, 2304LL * 512, 0, 512, YA, nullptr, 2);
  { long long yo[2] = {512, 2304LL * 1024 + 512};
    norm(YA, 2, 256, 2, 2304, A1B, CATB, 1024, yo, nullptr, 0, nullptr, nullptr); }

  // ec -> bn relu -> ef (f32) + fused gate partials
  gemm(0, 786432, 128, 256, 2304, 2, CATB, 2304LL * 1024, 512, 1024, YA, nullptr, 3);
  norm(YA, 3, 128, 2, 2304, nullptr, nullptr, 0, nullptr, EF, 1, GV, GACC);

  // mproj (fused im2col + sigmoid gate) -> bn relu -> cat[768:1024]
  gemm(2, 819200, 256, 1152, 576, 8, nullptr, 0, 0, 0, YA, nullptr, 4);
  { long long yo[8];
    for (int g = 0; g < 8; g++)
      yo[g] = (long long)(g >> 2) * 2304 * 1024 + (long long)(g & 3) * 576 * 1024 + 768;
    norm(YA, 4, 256, 8, 576, nullptr, CATB, 1024, yo, nullptr, 1, nullptr, nullptr); }

  // cv2 -> bn relu -> out (LDS-transposed)
  gemm(0, 1114112, 512, 1024, 2304, 2, CATB, 2304LL * 1024, 0, 1024, YA, nullptr, 5);
  k_normT<<<2304, 256, 0, stream>>>(YA, STB + 5 * 1024, out);
}